// Round 4
// baseline (96.082 us; speedup 1.0000x reference)
//
#include <hip/hip_runtime.h>
#include <math.h>

#define KTOP 200
#define NPART 32
#define BLOCK 1024
#define NV 4            // vehicles per block: each loaded point amortized over 4 key computations
#define NHIST 2048
#define CAND_CAP 512
#define WCAP 512
#define CLIST_CAP 1536  // expected qualifying keys ~650/vehicle; 1536 = big margin
#define SRANK_MIN 64u

// d2 exactly as numpy: ((dx*dx + dy*dy) + dz*dz), no fma contraction
__device__ __forceinline__ float d2_ref(float ax, float ay, float az,
                                        float bx, float by, float bz) {
    float dx = __fsub_rn(ax, bx), dy = __fsub_rn(ay, by), dz = __fsub_rn(az, bz);
    return __fadd_rn(__fadd_rn(__fmul_rn(dx, dx), __fmul_rn(dy, dy)), __fmul_rn(dz, dz));
}

__device__ __forceinline__ unsigned key2(float cx, float cy, float cz,
                                         float px, float py, float pz) {
    return __float_as_uint(d2_ref(cx, cy, cz, px, py, pz));
}

__device__ __forceinline__ unsigned key_of(const float* __restrict__ fus, int j,
                                           float vx, float vy, float vz) {
    return __float_as_uint(d2_ref(vx, vy, vz, fus[3*j], fus[3*j+1], fus[3*j+2]));
}

// shape-context bin of rel = p_j - q0, mirroring the reference f32 math
__device__ __forceinline__ int compute_bin(float rx, float ry, float rz) {
    const float TWO_PI_F = (float)6.283185307179586;
    const float PI_F     = (float)3.141592653589793;
    const float XY_W     = (float)(6.283185307179586 / 4.0);
    const float ZY_W     = (float)(3.141592653589793 / 4.0);

    float d2 = __fadd_rn(__fadd_rn(__fmul_rn(rx, rx), __fmul_rn(ry, ry)), __fmul_rn(rz, rz));
    float D  = sqrtf(__fadd_rn(d2, 1e-7f));
    float dist_bin;
    if (D >= 4.0f)      dist_bin = 1.0f;
    else if (D >= 1.0f) dist_bin = 0.0f;
    else                return -1;

    float axy = fmodf(atan2f(ry, rx) + TWO_PI_F, TWO_PI_F);
    float azy = fmodf(atan2f(ry, rz) + TWO_PI_F, PI_F);
    float xyb = floorf(__fdiv_rn(axy, XY_W));
    float zyb = floorf(__fdiv_rn(azy, ZY_W));
    if (!(xyb >= 0.0f && zyb >= 0.0f)) return -1;
    float ab  = xyb * 4.0f + zyb;
    int bin = (int)(dist_bin * 16.0f + ab);
    return bin;
}

__global__ __launch_bounds__(BLOCK, 4)
void shape_context_kernel(const float* __restrict__ veh,
                          const float* __restrict__ fus,
                          float* __restrict__ out,
                          int nfus, int nveh) {
    const int b    = blockIdx.x;
    const int tid  = threadIdx.x;
    const int lane = tid & 63;
    const int wid  = tid >> 6;
    const int vbase = b * NV;

    __shared__ unsigned int hist[NV][NHIST];            // 32 KB
    __shared__ unsigned long long clist[NV][CLIST_CAP]; // 48 KB
    __shared__ unsigned long long cand[CAND_CAP];       // 4 KB
    __shared__ int wlist[WCAP];                         // 2 KB
    __shared__ unsigned int hist32[NPART];
    __shared__ unsigned int waveTot[BLOCK / 64];
    __shared__ unsigned int waveBase[BLOCK / 64];
    __shared__ unsigned int s_bucket, s_rem, s_bcount;
    __shared__ int s_candCount, s_wcount, s_clistCount[NV];
    __shared__ unsigned int s_E[NV];
    __shared__ float s_q0[3];
    __shared__ unsigned long long s_minPacked, s_lowBound;

    // vehicle coords (tail block: clamped duplicates, output write guarded)
    const int vi0 = min(vbase + 0, nveh - 1), vi1 = min(vbase + 1, nveh - 1),
              vi2 = min(vbase + 2, nveh - 1), vi3 = min(vbase + 3, nveh - 1);
    const float cAx = veh[vi0*3], cAy = veh[vi0*3+1], cAz = veh[vi0*3+2];
    const float cBx = veh[vi1*3], cBy = veh[vi1*3+1], cBz = veh[vi1*3+2];
    const float cCx = veh[vi2*3], cCy = veh[vi2*3+1], cCz = veh[vi2*3+2];
    const float cDx = veh[vi3*3], cDy = veh[vi3*3+1], cDz = veh[vi3*3+2];

    const float4* fus4 = (const float4*)fus;
    const int ntrip = nfus >> 2;

    for (int i = tid; i < NV * NHIST; i += BLOCK) ((unsigned*)hist)[i] = 0;
    if (tid < NV) s_clistCount[tid] = 0;
    __syncthreads();

    // parallel "find bucket where cumulative count crosses remq" over h[NHIST]
    // leaves s_bucket = 0xFFFFFFFF if the cumulative never reaches remq
    auto find_bucket = [&](const unsigned* h, unsigned remq) {
        if (tid == 0) s_bucket = 0xFFFFFFFFu;
        const int PER = NHIST / BLOCK;  // 2
        int base = tid * PER;
        unsigned p = 0;
        #pragma unroll
        for (int i = 0; i < PER; i++) p += h[base + i];
        unsigned incl = p;
        #pragma unroll
        for (int d = 1; d < 64; d <<= 1) {
            unsigned n = __shfl_up(incl, d, 64);
            if (lane >= d) incl += n;
        }
        if (lane == 63) waveTot[wid] = incl;
        __syncthreads();
        if (tid == 0) {
            unsigned acc = 0;
            for (int w = 0; w < BLOCK / 64; w++) { waveBase[w] = acc; acc += waveTot[w]; }
        }
        __syncthreads();
        unsigned excl = waveBase[wid] + incl - p;
        if (excl < remq && remq <= excl + p) {
            unsigned cum = excl;
            #pragma unroll
            for (int i = 0; i < PER; i++) {
                unsigned c = h[base + i];
                if (cum + c >= remq) { s_bucket = base + i; s_rem = remq - cum; s_bcount = c; break; }
                cum += c;
            }
        }
        __syncthreads();
    };

    // list-only push (hist contribution already present)
    auto push_l = [&](int v, unsigned k, unsigned j) {
        int pos = atomicAdd(&s_clistCount[v], 1);
        if (pos < CLIST_CAP) clist[v][pos] = ((unsigned long long)k << 32) | j;
    };
    // hist + list push (stream keys)
    auto push_c = [&](int v, unsigned k, unsigned j) {
        atomicAdd(&hist[v][k >> 21], 1u);
        int pos = atomicAdd(&s_clistCount[v], 1);
        if (pos < CLIST_CAP) clist[v][pos] = ((unsigned long long)k << 32) | j;
    };

    // ---- sample phase: first 4*BLOCK points -> full histogram per vehicle ----
    const int t0n = (ntrip < BLOCK) ? ntrip : BLOCK;
    const bool t0v = (tid < t0n);
    float p0x=0,p0y=0,p0z=0, p1x=0,p1y=0,p1z=0, p2x=0,p2y=0,p2z=0, p3x=0,p3y=0,p3z=0;
    unsigned sA0=0,sA1=0,sA2=0,sA3=0, sB0=0,sB1=0,sB2=0,sB3=0;
    unsigned sC0=0,sC1=0,sC2=0,sC3=0, sD0=0,sD1=0,sD2=0,sD3=0;
    if (t0v) {
        float4 A = fus4[3*tid], Bq = fus4[3*tid+1], Cq = fus4[3*tid+2];
        p0x=A.x;  p0y=A.y;  p0z=A.z;
        p1x=A.w;  p1y=Bq.x; p1z=Bq.y;
        p2x=Bq.z; p2y=Bq.w; p2z=Cq.x;
        p3x=Cq.y; p3y=Cq.z; p3z=Cq.w;
        sA0=key2(cAx,cAy,cAz,p0x,p0y,p0z); sA1=key2(cAx,cAy,cAz,p1x,p1y,p1z);
        sA2=key2(cAx,cAy,cAz,p2x,p2y,p2z); sA3=key2(cAx,cAy,cAz,p3x,p3y,p3z);
        sB0=key2(cBx,cBy,cBz,p0x,p0y,p0z); sB1=key2(cBx,cBy,cBz,p1x,p1y,p1z);
        sB2=key2(cBx,cBy,cBz,p2x,p2y,p2z); sB3=key2(cBx,cBy,cBz,p3x,p3y,p3z);
        sC0=key2(cCx,cCy,cCz,p0x,p0y,p0z); sC1=key2(cCx,cCy,cCz,p1x,p1y,p1z);
        sC2=key2(cCx,cCy,cCz,p2x,p2y,p2z); sC3=key2(cCx,cCy,cCz,p3x,p3y,p3z);
        sD0=key2(cDx,cDy,cDz,p0x,p0y,p0z); sD1=key2(cDx,cDy,cDz,p1x,p1y,p1z);
        sD2=key2(cDx,cDy,cDz,p2x,p2y,p2z); sD3=key2(cDx,cDy,cDz,p3x,p3y,p3z);
        atomicAdd(&hist[0][sA0>>21],1u); atomicAdd(&hist[0][sA1>>21],1u);
        atomicAdd(&hist[0][sA2>>21],1u); atomicAdd(&hist[0][sA3>>21],1u);
        atomicAdd(&hist[1][sB0>>21],1u); atomicAdd(&hist[1][sB1>>21],1u);
        atomicAdd(&hist[1][sB2>>21],1u); atomicAdd(&hist[1][sB3>>21],1u);
        atomicAdd(&hist[2][sC0>>21],1u); atomicAdd(&hist[2][sC1>>21],1u);
        atomicAdd(&hist[2][sC2>>21],1u); atomicAdd(&hist[2][sC3>>21],1u);
        atomicAdd(&hist[3][sD0>>21],1u); atomicAdd(&hist[3][sD1>>21],1u);
        atomicAdd(&hist[3][sD2>>21],1u); atomicAdd(&hist[3][sD3>>21],1u);
    }
    __syncthreads();

    // ---- per-vehicle conservative bound E_v from the sample ----
    unsigned srank;
    {
        long long sample = 4LL * t0n;
        if (sample >= (long long)nfus) {
            srank = KTOP;  // sample is the whole population -> exact
        } else {
            unsigned s2 = (unsigned)((3LL * KTOP * sample + nfus - 1) / nfus);
            srank = (s2 < SRANK_MIN) ? SRANK_MIN : s2;
        }
    }
    find_bucket(hist[0], srank);
    const unsigned E0 = (s_bucket < NHIST) ? s_bucket : (NHIST-1);
    if (tid == 0) s_E[0] = E0;
    __syncthreads();
    find_bucket(hist[1], srank);
    const unsigned E1 = (s_bucket < NHIST) ? s_bucket : (NHIST-1);
    if (tid == 0) s_E[1] = E1;
    __syncthreads();
    find_bucket(hist[2], srank);
    const unsigned E2 = (s_bucket < NHIST) ? s_bucket : (NHIST-1);
    if (tid == 0) s_E[2] = E2;
    __syncthreads();
    find_bucket(hist[3], srank);
    const unsigned E3 = (s_bucket < NHIST) ? s_bucket : (NHIST-1);
    if (tid == 0) s_E[3] = E3;
    __syncthreads();
    // all keys <= mk lie in buckets <= E (positive-float bit order == value order)
    const unsigned mk0 = ((E0+1u)<<21)-1u, mk1 = ((E1+1u)<<21)-1u;
    const unsigned mk2 = ((E2+1u)<<21)-1u, mk3 = ((E3+1u)<<21)-1u;

    // sample keys: already in hist; push qualifiers into clists (list only)
    if (t0v) {
        unsigned jb = 4u * (unsigned)tid;
        if (sA0<=mk0) push_l(0,sA0,jb+0); if (sA1<=mk0) push_l(0,sA1,jb+1);
        if (sA2<=mk0) push_l(0,sA2,jb+2); if (sA3<=mk0) push_l(0,sA3,jb+3);
        if (sB0<=mk1) push_l(1,sB0,jb+0); if (sB1<=mk1) push_l(1,sB1,jb+1);
        if (sB2<=mk1) push_l(1,sB2,jb+2); if (sB3<=mk1) push_l(1,sB3,jb+3);
        if (sC0<=mk2) push_l(2,sC0,jb+0); if (sC1<=mk2) push_l(2,sC1,jb+1);
        if (sC2<=mk2) push_l(2,sC2,jb+2); if (sC3<=mk2) push_l(2,sC3,jb+3);
        if (sD0<=mk3) push_l(3,sD0,jb+0); if (sD1<=mk3) push_l(3,sD1,jb+1);
        if (sD2<=mk3) push_l(3,sD2,jb+2); if (sD3<=mk3) push_l(3,sD3,jb+3);
    }

    // ---- main stream: 1 trip load -> 16 keys; no barriers; ~3% take the push ----
    for (int m = BLOCK + tid; m < ntrip; m += BLOCK) {
        float4 A = fus4[3*m], Bq = fus4[3*m+1], Cq = fus4[3*m+2];
        float x0=A.x,  y0=A.y,  z0=A.z;
        float x1=A.w,  y1=Bq.x, z1=Bq.y;
        float x2=Bq.z, y2=Bq.w, z2=Cq.x;
        float x3=Cq.y, y3=Cq.z, z3=Cq.w;
        unsigned jb = 4u * (unsigned)m;
        {
            unsigned k0=key2(cAx,cAy,cAz,x0,y0,z0), k1=key2(cAx,cAy,cAz,x1,y1,z1);
            unsigned k2=key2(cAx,cAy,cAz,x2,y2,z2), k3=key2(cAx,cAy,cAz,x3,y3,z3);
            if ((k0<=mk0)|(k1<=mk0)|(k2<=mk0)|(k3<=mk0)) {
                if (k0<=mk0) push_c(0,k0,jb+0); if (k1<=mk0) push_c(0,k1,jb+1);
                if (k2<=mk0) push_c(0,k2,jb+2); if (k3<=mk0) push_c(0,k3,jb+3);
            }
        }
        {
            unsigned k0=key2(cBx,cBy,cBz,x0,y0,z0), k1=key2(cBx,cBy,cBz,x1,y1,z1);
            unsigned k2=key2(cBx,cBy,cBz,x2,y2,z2), k3=key2(cBx,cBy,cBz,x3,y3,z3);
            if ((k0<=mk1)|(k1<=mk1)|(k2<=mk1)|(k3<=mk1)) {
                if (k0<=mk1) push_c(1,k0,jb+0); if (k1<=mk1) push_c(1,k1,jb+1);
                if (k2<=mk1) push_c(1,k2,jb+2); if (k3<=mk1) push_c(1,k3,jb+3);
            }
        }
        {
            unsigned k0=key2(cCx,cCy,cCz,x0,y0,z0), k1=key2(cCx,cCy,cCz,x1,y1,z1);
            unsigned k2=key2(cCx,cCy,cCz,x2,y2,z2), k3=key2(cCx,cCy,cCz,x3,y3,z3);
            if ((k0<=mk2)|(k1<=mk2)|(k2<=mk2)|(k3<=mk2)) {
                if (k0<=mk2) push_c(2,k0,jb+0); if (k1<=mk2) push_c(2,k1,jb+1);
                if (k2<=mk2) push_c(2,k2,jb+2); if (k3<=mk2) push_c(2,k3,jb+3);
            }
        }
        {
            unsigned k0=key2(cDx,cDy,cDz,x0,y0,z0), k1=key2(cDx,cDy,cDz,x1,y1,z1);
            unsigned k2=key2(cDx,cDy,cDz,x2,y2,z2), k3=key2(cDx,cDy,cDz,x3,y3,z3);
            if ((k0<=mk3)|(k1<=mk3)|(k2<=mk3)|(k3<=mk3)) {
                if (k0<=mk3) push_c(3,k0,jb+0); if (k1<=mk3) push_c(3,k1,jb+1);
                if (k2<=mk3) push_c(3,k2,jb+2); if (k3<=mk3) push_c(3,k3,jb+3);
            }
        }
    }
    // tail (nfus % 4)
    for (int j = (nfus & ~3) + tid; j < nfus; j += BLOCK) {
        float fx = fus[3*j], fy = fus[3*j+1], fz = fus[3*j+2];
        unsigned k;
        k = key2(cAx,cAy,cAz,fx,fy,fz); if (k<=mk0) push_c(0,k,(unsigned)j);
        k = key2(cBx,cBy,cBz,fx,fy,fz); if (k<=mk1) push_c(1,k,(unsigned)j);
        k = key2(cCx,cCy,cCz,fx,fy,fz); if (k<=mk2) push_c(2,k,(unsigned)j);
        k = key2(cDx,cDy,cDz,fx,fy,fz); if (k<=mk3) push_c(3,k,(unsigned)j);
    }
    __syncthreads();

    // ---- per-vehicle selection + binning + epilogue (cheap: ~650-entry walks) ----
    for (int v = 0; v < NV; ++v) {
        unsigned* hv = hist[v];
        unsigned long long* clv = clist[v];
        const int vi = min(vbase + v, nveh - 1);
        const float vxv = veh[vi*3], vyv = veh[vi*3+1], vzv = veh[vi*3+2];

        if (tid == 0) { s_minPacked = ~0ull; s_candCount = 0; s_wcount = 0; }
        if (tid < NPART) hist32[tid] = 0;
        __syncthreads();

        // hv exact on [0, E_v]; garbage above. Crossing at T <= E_v is exact.
        find_bucket(hv, KTOP);
        unsigned T = s_bucket, rem = s_rem, bcount = s_bcount;
        int shift = 21;
        const bool fastOK = (s_clistCount[v] <= CLIST_CAP) && (T <= s_E[v]);

        if (fastOK) {
            // argmin (= top-1, always bucket <= E, always in clist) from the compact list
            const int cn = s_clistCount[v];
            unsigned long long lm = ~0ull;
            for (int i = tid; i < cn; i += BLOCK) { unsigned long long p = clv[i]; lm = (p < lm) ? p : lm; }
            #pragma unroll
            for (int d = 32; d > 0; d >>= 1) {
                unsigned long long o = __shfl_xor(lm, d, 64);
                lm = (o < lm) ? o : lm;
            }
            if (lane == 0) atomicMin(&s_minPacked, lm);
            __syncthreads();
        } else {
            // rare: bound failed or clist overflowed -> rebuild full exact histogram + argmin
            for (int i = tid; i < NHIST; i += BLOCK) hv[i] = 0;
            __syncthreads();
            unsigned long long lm = ~0ull;
            for (int j = tid; j < nfus; j += BLOCK) {
                unsigned k = key_of(fus, j, vxv, vyv, vzv);
                atomicAdd(&hv[k >> 21], 1u);
                unsigned long long p = ((unsigned long long)k << 32) | (unsigned)j;
                lm = (p < lm) ? p : lm;
            }
            #pragma unroll
            for (int d = 32; d > 0; d >>= 1) {
                unsigned long long o = __shfl_xor(lm, d, 64);
                lm = (o < lm) ? o : lm;
            }
            if (lane == 0) atomicMin(&s_minPacked, lm);
            __syncthreads();
            find_bucket(hv, KTOP);
            T = s_bucket; rem = s_rem; bcount = s_bcount;
        }

        if (tid == 0) {
            int idx0 = (int)(s_minPacked & 0xFFFFFFFFull);
            s_q0[0] = fus[idx0*3]; s_q0[1] = fus[idx0*3+1]; s_q0[2] = fus[idx0*3+2];
        }
        __syncthreads();
        const float q0x = s_q0[0], q0y = s_q0[1], q0z = s_q0[2];

        // rare: refine threshold bucket if too many candidates (reload-based)
        while (bcount > CAND_CAP && shift > 0) {
            int newshift = (shift > 11) ? (shift - 11) : 0;
            unsigned digmask = (1u << (shift - newshift)) - 1;
            for (int i = tid; i < NHIST; i += BLOCK) hv[i] = 0;
            __syncthreads();
            for (int j = tid; j < nfus; j += BLOCK) {
                unsigned k = key_of(fus, j, vxv, vyv, vzv);
                if ((k >> shift) == T) atomicAdd(&hv[(k >> newshift) & digmask], 1u);
            }
            __syncthreads();
            find_bucket(hv, rem);
            T = (T << (shift - newshift)) | s_bucket;
            rem = s_rem;
            bcount = s_bcount;
            shift = newshift;
        }

        // scan B: winners -> wlist, boundary bucket -> cand
        if (fastOK && shift == 21) {
            const int cn = s_clistCount[v];
            for (int i = tid; i < cn; i += BLOCK) {
                unsigned long long p = clv[i];
                unsigned hi = (unsigned)(p >> 53);   // == key >> 21
                if (hi < T) {
                    int pos = atomicAdd(&s_wcount, 1);
                    if (pos < WCAP) wlist[pos] = (int)(p & 0xFFFFFFFFull);
                } else if (hi == T) {
                    int pos = atomicAdd(&s_candCount, 1);
                    if (pos < CAND_CAP) cand[pos] = p;
                }
            }
        } else {
            for (int j = tid; j < nfus; j += BLOCK) {
                unsigned k = key_of(fus, j, vxv, vyv, vzv);
                unsigned hi = k >> shift;
                if (hi < T) { int pos = atomicAdd(&s_wcount, 1); if (pos < WCAP) wlist[pos] = j; }
                else if (hi == T) { int pos = atomicAdd(&s_candCount, 1); if (pos < CAND_CAP) cand[pos] = ((unsigned long long)k << 32) | (unsigned)j; }
            }
        }
        __syncthreads();

        const int cnt = s_candCount;
        if (cnt <= CAND_CAP) {
            // exact stable ranking among boundary candidates by (key, idx)
            for (int i = tid; i < cnt; i += BLOCK) {
                unsigned long long me = cand[i];
                int rank = 0;
                for (int k2 = 0; k2 < cnt; k2++) rank += (cand[k2] < me) ? 1 : 0;
                if (rank < (int)rem) {
                    int pos = atomicAdd(&s_wcount, 1);
                    if (pos < WCAP) wlist[pos] = (int)(me & 0xFFFFFFFFull);
                }
            }
        }
        __syncthreads();

        // compact winner processing
        {
            int wc = s_wcount; if (wc > WCAP) wc = WCAP;
            for (int i = tid; i < wc; i += BLOCK) {
                int j = wlist[i];
                float fx = fus[3*j], fy = fus[3*j+1], fz = fus[3*j+2];
                int bin = compute_bin(__fsub_rn(fx, q0x), __fsub_rn(fy, q0y), __fsub_rn(fz, q0z));
                if (bin >= 0 && bin < NPART) atomicAdd(&hist32[bin], 1u);
            }
        }
        __syncthreads();

        if (cnt > CAND_CAP) {
            // pathological fallback: serial extraction of `rem` smallest in bucket T
            if (tid == 0) s_lowBound = 0;
            __syncthreads();
            for (unsigned itx = 0; itx < rem; ++itx) {
                if (tid == 0) s_minPacked = ~0ull;
                __syncthreads();
                unsigned long long lowB = s_lowBound;
                unsigned long long lm = ~0ull;
                for (int j = tid; j < nfus; j += BLOCK) {
                    unsigned k = key_of(fus, j, vxv, vyv, vzv);
                    if ((k >> shift) == T) {
                        unsigned long long p = ((unsigned long long)k << 32) | (unsigned)j;
                        if (p >= lowB && p < lm) lm = p;
                    }
                }
                #pragma unroll
                for (int d = 32; d > 0; d >>= 1) {
                    unsigned long long o = __shfl_xor(lm, d, 64);
                    lm = (o < lm) ? o : lm;
                }
                if (lane == 0) atomicMin(&s_minPacked, lm);
                __syncthreads();
                if (tid == 0) {
                    int jm = (int)(s_minPacked & 0xFFFFFFFFull);
                    float fx = fus[jm*3], fy = fus[jm*3+1], fz = fus[jm*3+2];
                    int bin = compute_bin(__fsub_rn(fx, q0x), __fsub_rn(fy, q0y), __fsub_rn(fz, q0z));
                    if (bin >= 0 && bin < NPART) hist32[bin] += 1u;
                    s_lowBound = s_minPacked + 1;
                }
                __syncthreads();
            }
        }

        // epilogue (32 lanes of wave 0): counts+1 -> L2-normalize*4 -> softmax
        if (tid < NPART) {
            float c = (float)hist32[tid] + 1.0f;
            float ss = __fmul_rn(c, c);
            #pragma unroll
            for (int d = 16; d > 0; d >>= 1) ss += __shfl_xor(ss, d, 64);
            float vv = __fmul_rn(__fdiv_rn(c, sqrtf(ss)), 4.0f);
            float mx = vv;
            #pragma unroll
            for (int d = 16; d > 0; d >>= 1) mx = fmaxf(mx, __shfl_xor(mx, d, 64));
            float e = expf(vv - mx);
            float sum = e;
            #pragma unroll
            for (int d = 16; d > 0; d >>= 1) sum += __shfl_xor(sum, d, 64);
            if (vbase + v < nveh) out[(vbase + v) * NPART + tid] = __fdiv_rn(e, sum);
        }
        __syncthreads();
    }
}

extern "C" void kernel_launch(void* const* d_in, const int* in_sizes, int n_in,
                              void* d_out, int out_size, void* d_ws, size_t ws_size,
                              hipStream_t stream) {
    const float* veh = (const float*)d_in[0];   // (1024, 3)
    const float* fus = (const float*)d_in[1];   // (20000, 3)
    float* out = (float*)d_out;                 // (1024, 32)
    int nveh = in_sizes[0] / 3;
    int nfus = in_sizes[1] / 3;
    int nblocks = (nveh + NV - 1) / NV;
    shape_context_kernel<<<nblocks, BLOCK, 0, stream>>>(veh, fus, out, nfus, nveh);
}

// Round 5
// 77.226 us; speedup vs baseline: 1.2442x; 1.2442x over previous
//
#include <hip/hip_runtime.h>
#include <math.h>

#define KTOP 200
#define NPART 32
#define BLOCK 512
#define NHIST 2048
#define CAND_CAP 512
#define WCAP 512
#define CLIST_CAP 1536   // expected qualifying keys ~650 (srank=64 * nfus/sample); 1536 = big margin
#define SRANK_MIN 64u    // sample rank for bound E; 64 => ~17 sigma margin that exact count(<=E) >= KTOP

// d2 exactly as numpy: ((dx*dx + dy*dy) + dz*dz), no fma contraction
__device__ __forceinline__ float d2_ref(float ax, float ay, float az,
                                        float bx, float by, float bz) {
    float dx = __fsub_rn(ax, bx), dy = __fsub_rn(ay, by), dz = __fsub_rn(az, bz);
    return __fadd_rn(__fadd_rn(__fmul_rn(dx, dx), __fmul_rn(dy, dy)), __fmul_rn(dz, dz));
}

__device__ __forceinline__ unsigned key_of(const float* __restrict__ fus, int j,
                                           float vx, float vy, float vz) {
    return __float_as_uint(d2_ref(vx, vy, vz, fus[3*j], fus[3*j+1], fus[3*j+2]));
}

// shape-context bin of rel = p_j - q0, mirroring the reference f32 math
__device__ __forceinline__ int compute_bin(float rx, float ry, float rz) {
    const float TWO_PI_F = (float)6.283185307179586;
    const float PI_F     = (float)3.141592653589793;
    const float XY_W     = (float)(6.283185307179586 / 4.0);
    const float ZY_W     = (float)(3.141592653589793 / 4.0);

    float d2 = __fadd_rn(__fadd_rn(__fmul_rn(rx, rx), __fmul_rn(ry, ry)), __fmul_rn(rz, rz));
    float D  = sqrtf(__fadd_rn(d2, 1e-7f));
    float dist_bin;
    if (D >= 4.0f)      dist_bin = 1.0f;
    else if (D >= 1.0f) dist_bin = 0.0f;
    else                return -1;

    float axy = fmodf(atan2f(ry, rx) + TWO_PI_F, TWO_PI_F);
    float azy = fmodf(atan2f(ry, rz) + TWO_PI_F, PI_F);
    float xyb = floorf(__fdiv_rn(axy, XY_W));
    float zyb = floorf(__fdiv_rn(azy, ZY_W));
    if (!(xyb >= 0.0f && zyb >= 0.0f)) return -1;
    float ab  = xyb * 4.0f + zyb;
    int bin = (int)(dist_bin * 16.0f + ab);
    return bin;
}

__global__ __launch_bounds__(BLOCK, 8)
void shape_context_kernel(const float* __restrict__ veh,
                          const float* __restrict__ fus,
                          float* __restrict__ out,
                          int nfus) {
    const int b   = blockIdx.x;
    const int tid = threadIdx.x;
    const int lane = tid & 63;
    const int wid  = tid >> 6;

    __shared__ unsigned int hist[NHIST];
    __shared__ unsigned long long clist[CLIST_CAP];  // packed (key<<32 | idx), keys with bucket <= E
    __shared__ unsigned long long cand[CAND_CAP];
    __shared__ int wlist[WCAP];
    __shared__ unsigned int hist32[NPART];
    __shared__ unsigned int waveTot[BLOCK / 64];
    __shared__ unsigned int waveBase[BLOCK / 64];
    __shared__ unsigned int s_bucket, s_rem, s_bcount;
    __shared__ int s_candCount, s_wcount, s_clistCount;
    __shared__ float s_q0[3];
    __shared__ unsigned long long s_minPacked, s_lowBound;

    const float vx = veh[b * 3 + 0], vy = veh[b * 3 + 1], vz = veh[b * 3 + 2];
    const float4* fus4 = (const float4*)fus;
    const int ntrip = nfus >> 2;

    if (tid == 0) { s_minPacked = ~0ull; s_candCount = 0; s_wcount = 0; s_clistCount = 0; }
    for (int i = tid; i < NHIST; i += BLOCK) hist[i] = 0;
    if (tid < NPART) hist32[tid] = 0;
    __syncthreads();

    // parallel "find bucket where cumulative count crosses remq" over hist[NHIST]
    // leaves s_bucket = 0xFFFFFFFF if the cumulative never reaches remq
    auto find_bucket = [&](unsigned remq) {
        if (tid == 0) s_bucket = 0xFFFFFFFFu;
        const int PER = NHIST / BLOCK;  // 4
        int base = tid * PER;
        unsigned p = 0;
        #pragma unroll
        for (int i = 0; i < PER; i++) p += hist[base + i];
        unsigned incl = p;
        #pragma unroll
        for (int d = 1; d < 64; d <<= 1) {
            unsigned n = __shfl_up(incl, d, 64);
            if (lane >= d) incl += n;
        }
        if (lane == 63) waveTot[wid] = incl;
        __syncthreads();
        if (tid == 0) {
            unsigned acc = 0;
            for (int w = 0; w < BLOCK / 64; w++) { waveBase[w] = acc; acc += waveTot[w]; }
        }
        __syncthreads();
        unsigned excl = waveBase[wid] + incl - p;
        if (excl < remq && remq <= excl + p) {
            unsigned cum = excl;
            #pragma unroll
            for (int i = 0; i < PER; i++) {
                unsigned c = hist[base + i];
                if (cum + c >= remq) { s_bucket = base + i; s_rem = remq - cum; s_bcount = c; break; }
                cum += c;
            }
        }
        __syncthreads();
    };

    // per-lane push (sample/tail only; stream uses wave-aggregated path)
    auto push_l = [&](unsigned k, unsigned j) {
        int pos = atomicAdd(&s_clistCount, 1);
        if (pos < CLIST_CAP) clist[pos] = ((unsigned long long)k << 32) | j;
    };

    // ---- trip 0: full histogram of the first 4*BLOCK points (i.i.d. random sample) ----
    unsigned k0 = 0, k1 = 0, k2 = 0, k3 = 0;
    const bool t0v = (tid < ntrip);
    if (t0v) {
        float4 A = fus4[3 * tid], Bq = fus4[3 * tid + 1], Cq = fus4[3 * tid + 2];
        k0 = __float_as_uint(d2_ref(vx, vy, vz, A.x,  A.y,  A.z));
        k1 = __float_as_uint(d2_ref(vx, vy, vz, A.w,  Bq.x, Bq.y));
        k2 = __float_as_uint(d2_ref(vx, vy, vz, Bq.z, Bq.w, Cq.x));
        k3 = __float_as_uint(d2_ref(vx, vy, vz, Cq.y, Cq.z, Cq.w));
        atomicAdd(&hist[k0 >> 21], 1u);
        atomicAdd(&hist[k1 >> 21], 1u);
        atomicAdd(&hist[k2 >> 21], 1u);
        atomicAdd(&hist[k3 >> 21], 1u);
    }
    __syncthreads();

    // ---- E: conservative upper-bound bucket for the KTOP-th key, from the sample ----
    unsigned srank;
    {
        long long sample = (long long)((ntrip < BLOCK) ? ntrip : BLOCK) * 4;
        if (sample >= (long long)nfus) {
            srank = KTOP;  // sample is the whole population -> exact
        } else {
            unsigned s2 = (unsigned)(((long long)3 * KTOP * sample + nfus - 1) / nfus);
            srank = (s2 < SRANK_MIN) ? SRANK_MIN : s2;
        }
    }
    find_bucket(srank);
    const unsigned E = (s_bucket < NHIST) ? s_bucket : (NHIST - 1);  // unset -> no filtering
    // all keys <= maxKey lie in buckets <= E (positive-float bit order == value order)
    const unsigned maxKey = ((E + 1u) << 21) - 1u;

    // sample keys: push qualifiers into clist (hist on [0,E] is rebuilt from clist later)
    if (t0v) {
        unsigned jb = 4u * (unsigned)tid;
        if (k0 <= maxKey) push_l(k0, jb + 0);
        if (k1 <= maxKey) push_l(k1, jb + 1);
        if (k2 <= maxKey) push_l(k2, jb + 2);
        if (k3 <= maxKey) push_l(k3, jb + 3);
    }

    // ---- main stream: 1 uint compare per key; wave-aggregated push (ONE LDS atomic
    //      round-trip per wave-trip instead of ~3.5 dependent chains); no hist atomics ----
    {
        int m = BLOCK + tid;
        bool valid = (m < ntrip);
        float4 A, Bq, Cq;
        if (valid) { A = fus4[3 * m]; Bq = fus4[3 * m + 1]; Cq = fus4[3 * m + 2]; }
        while (valid) {
            const int mn = m + BLOCK;
            const bool vnext = (mn < ntrip);
            float4 An, Bn, Cn;
            if (vnext) { An = fus4[3 * mn]; Bn = fus4[3 * mn + 1]; Cn = fus4[3 * mn + 2]; }

            unsigned q0k = __float_as_uint(d2_ref(vx, vy, vz, A.x,  A.y,  A.z));
            unsigned q1k = __float_as_uint(d2_ref(vx, vy, vz, A.w,  Bq.x, Bq.y));
            unsigned q2k = __float_as_uint(d2_ref(vx, vy, vz, Bq.z, Bq.w, Cq.x));
            unsigned q3k = __float_as_uint(d2_ref(vx, vy, vz, Cq.y, Cq.z, Cq.w));
            // loop-exit drops HIGH lanes first (m grows with lane) => lane 0 active
            // whenever any lane is, so the lane-0 atomic below is safe.
            unsigned long long m0 = __ballot(q0k <= maxKey);
            unsigned long long m1 = __ballot(q1k <= maxKey);
            unsigned long long m2 = __ballot(q2k <= maxKey);
            unsigned long long m3 = __ballot(q3k <= maxKey);
            if (m0 | m1 | m2 | m3) {             // wave-uniform branch
                int c0 = __popcll(m0), c1 = __popcll(m1), c2 = __popcll(m2);
                int tot = c0 + c1 + c2 + __popcll(m3);
                int base = 0;
                if (lane == 0) base = atomicAdd(&s_clistCount, tot);
                base = __shfl(base, 0, 64);
                const unsigned long long lt = (1ull << lane) - 1ull;
                unsigned jb = 4u * (unsigned)m;
                int o0 = base + (int)__popcll(m0 & lt);
                int o1 = base + c0 + (int)__popcll(m1 & lt);
                int o2 = base + c0 + c1 + (int)__popcll(m2 & lt);
                int o3 = base + c0 + c1 + c2 + (int)__popcll(m3 & lt);
                if (q0k <= maxKey && o0 < CLIST_CAP) clist[o0] = ((unsigned long long)q0k << 32) | (jb + 0);
                if (q1k <= maxKey && o1 < CLIST_CAP) clist[o1] = ((unsigned long long)q1k << 32) | (jb + 1);
                if (q2k <= maxKey && o2 < CLIST_CAP) clist[o2] = ((unsigned long long)q2k << 32) | (jb + 2);
                if (q3k <= maxKey && o3 < CLIST_CAP) clist[o3] = ((unsigned long long)q3k << 32) | (jb + 3);
            }
            A = An; Bq = Bn; Cq = Cn; m = mn; valid = vnext;
        }
    }
    // tail (nfus % 4): at most 3 points, per-lane push
    for (int j = (nfus & ~3) + tid; j < nfus; j += BLOCK) {
        unsigned k = key_of(fus, j, vx, vy, vz);
        if (k <= maxKey) push_l(k, (unsigned)j);
    }
    __syncthreads();

    // ---- rebuild exact hist on [0, E] from clist (no overflow => clist is the exact
    //      multiset of keys with bucket <= E, sample included) ----
    const int cnRaw = s_clistCount;
    const bool noOvf = (cnRaw <= CLIST_CAP);
    if (noOvf) {
        for (int i = tid; i <= (int)E; i += BLOCK) hist[i] = 0;
        __syncthreads();
        for (int i = tid; i < cnRaw; i += BLOCK)
            atomicAdd(&hist[(unsigned)(clist[i] >> 53)], 1u);
        __syncthreads();
    }

    // hist exact on [0, E]; garbage (sample-only) above E. A crossing at T <= E is exact.
    find_bucket(KTOP);
    unsigned T = s_bucket;
    unsigned rem = s_rem;
    unsigned bcount = s_bcount;
    int shift = 21;
    const bool fastOK = noOvf && (T <= E);

    if (fastOK) {
        // argmin (= top-1, always bucket <= E, always in clist) from the compact list
        unsigned long long lm = ~0ull;
        for (int i = tid; i < cnRaw; i += BLOCK) { unsigned long long p = clist[i]; lm = (p < lm) ? p : lm; }
        #pragma unroll
        for (int d = 32; d > 0; d >>= 1) {
            unsigned long long o = __shfl_xor(lm, d, 64);
            lm = (o < lm) ? o : lm;
        }
        if (lane == 0) atomicMin(&s_minPacked, lm);
        __syncthreads();
    } else {
        // rare: bound E failed or clist overflowed -> rebuild full exact histogram + argmin
        for (int i = tid; i < NHIST; i += BLOCK) hist[i] = 0;
        __syncthreads();
        unsigned long long lm = ~0ull;
        for (int j = tid; j < nfus; j += BLOCK) {
            unsigned k = key_of(fus, j, vx, vy, vz);
            atomicAdd(&hist[k >> 21], 1u);
            unsigned long long p = ((unsigned long long)k << 32) | (unsigned)j;
            lm = (p < lm) ? p : lm;
        }
        #pragma unroll
        for (int d = 32; d > 0; d >>= 1) {
            unsigned long long o = __shfl_xor(lm, d, 64);
            lm = (o < lm) ? o : lm;
        }
        if (lane == 0) atomicMin(&s_minPacked, lm);
        __syncthreads();
        find_bucket(KTOP);
        T = s_bucket; rem = s_rem; bcount = s_bcount;
    }

    if (tid == 0) {
        int idx0 = (int)(s_minPacked & 0xFFFFFFFFull);
        s_q0[0] = fus[idx0 * 3]; s_q0[1] = fus[idx0 * 3 + 1]; s_q0[2] = fus[idx0 * 3 + 2];
    }
    __syncthreads();
    const float q0x = s_q0[0], q0y = s_q0[1], q0z = s_q0[2];

    // ---- rare: refine threshold bucket if too many candidates (reload-based) ----
    while (bcount > CAND_CAP && shift > 0) {
        int newshift = (shift > 11) ? (shift - 11) : 0;
        unsigned digmask = (1u << (shift - newshift)) - 1;
        for (int i = tid; i < NHIST; i += BLOCK) hist[i] = 0;
        __syncthreads();
        for (int j = tid; j < nfus; j += BLOCK) {
            unsigned k = key_of(fus, j, vx, vy, vz);
            if ((k >> shift) == T) atomicAdd(&hist[(k >> newshift) & digmask], 1u);
        }
        __syncthreads();
        find_bucket(rem);
        T = (T << (shift - newshift)) | s_bucket;
        rem = s_rem;
        bcount = s_bcount;
        shift = newshift;
    }

    // ---- scan B: winners -> wlist, boundary bucket -> cand ----
    if (fastOK && shift == 21) {
        // walk the compact candidate list (exact packed keys, ~650 entries)
        for (int i = tid; i < cnRaw; i += BLOCK) {
            unsigned long long p = clist[i];
            unsigned hi = (unsigned)(p >> 53);   // == key >> 21
            if (hi < T) {
                int pos = atomicAdd(&s_wcount, 1);
                if (pos < WCAP) wlist[pos] = (int)(p & 0xFFFFFFFFull);
            } else if (hi == T) {
                int pos = atomicAdd(&s_candCount, 1);
                if (pos < CAND_CAP) cand[pos] = p;
            }
        }
    } else {
        for (int j = tid; j < nfus; j += BLOCK) {
            unsigned k = key_of(fus, j, vx, vy, vz);
            unsigned hi = k >> shift;
            if (hi < T) { int pos = atomicAdd(&s_wcount, 1); if (pos < WCAP) wlist[pos] = j; }
            else if (hi == T) { int pos = atomicAdd(&s_candCount, 1); if (pos < CAND_CAP) cand[pos] = ((unsigned long long)k << 32) | (unsigned)j; }
        }
    }
    __syncthreads();

    const int cnt = s_candCount;
    if (cnt <= CAND_CAP) {
        // exact stable ranking among boundary candidates by (key, idx); qualifiers join wlist
        for (int i = tid; i < cnt; i += BLOCK) {
            unsigned long long me = cand[i];
            int rank = 0;
            for (int k2 = 0; k2 < cnt; k2++) rank += (cand[k2] < me) ? 1 : 0;
            if (rank < (int)rem) {
                int pos = atomicAdd(&s_wcount, 1);
                if (pos < WCAP) wlist[pos] = (int)(me & 0xFFFFFFFFull);
            }
        }
    }
    __syncthreads();

    // ---- compact winner processing: ~one compute_bin per thread ----
    {
        int wc = s_wcount; if (wc > WCAP) wc = WCAP;
        for (int i = tid; i < wc; i += BLOCK) {
            int j = wlist[i];
            float fx = fus[3 * j], fy = fus[3 * j + 1], fz = fus[3 * j + 2];
            int bin = compute_bin(__fsub_rn(fx, q0x), __fsub_rn(fy, q0y), __fsub_rn(fz, q0z));
            if (bin >= 0 && bin < NPART) atomicAdd(&hist32[bin], 1u);
        }
    }
    __syncthreads();

    if (cnt > CAND_CAP) {
        // pathological fallback: serial extraction of `rem` smallest packed (key,idx) in bucket T
        if (tid == 0) s_lowBound = 0;
        __syncthreads();
        for (unsigned itx = 0; itx < rem; ++itx) {
            if (tid == 0) s_minPacked = ~0ull;
            __syncthreads();
            unsigned long long lowB = s_lowBound;
            unsigned long long lm = ~0ull;
            for (int j = tid; j < nfus; j += BLOCK) {
                unsigned k = key_of(fus, j, vx, vy, vz);
                if ((k >> shift) == T) {
                    unsigned long long p = ((unsigned long long)k << 32) | (unsigned)j;
                    if (p >= lowB && p < lm) lm = p;
                }
            }
            #pragma unroll
            for (int d = 32; d > 0; d >>= 1) {
                unsigned long long o = __shfl_xor(lm, d, 64);
                lm = (o < lm) ? o : lm;
            }
            if (lane == 0) atomicMin(&s_minPacked, lm);
            __syncthreads();
            if (tid == 0) {
                int jm = (int)(s_minPacked & 0xFFFFFFFFull);
                float fx = fus[jm * 3], fy = fus[jm * 3 + 1], fz = fus[jm * 3 + 2];
                int bin = compute_bin(__fsub_rn(fx, q0x), __fsub_rn(fy, q0y), __fsub_rn(fz, q0z));
                if (bin >= 0 && bin < NPART) hist32[bin] += 1u;
                s_lowBound = s_minPacked + 1;
            }
            __syncthreads();
        }
    }

    // ---- epilogue (32 lanes of wave 0): counts+1 -> L2-normalize*4 -> softmax ----
    if (tid < NPART) {
        float c = (float)hist32[tid] + 1.0f;
        float ss = __fmul_rn(c, c);
        #pragma unroll
        for (int d = 16; d > 0; d >>= 1) ss += __shfl_xor(ss, d, 64);
        float v = __fmul_rn(__fdiv_rn(c, sqrtf(ss)), 4.0f);
        float mx = v;
        #pragma unroll
        for (int d = 16; d > 0; d >>= 1) mx = fmaxf(mx, __shfl_xor(mx, d, 64));
        float e = expf(v - mx);
        float sum = e;
        #pragma unroll
        for (int d = 16; d > 0; d >>= 1) sum += __shfl_xor(sum, d, 64);
        out[b * NPART + tid] = __fdiv_rn(e, sum);
    }
}

extern "C" void kernel_launch(void* const* d_in, const int* in_sizes, int n_in,
                              void* d_out, int out_size, void* d_ws, size_t ws_size,
                              hipStream_t stream) {
    const float* veh = (const float*)d_in[0];   // (1024, 3)
    const float* fus = (const float*)d_in[1];   // (20000, 3)
    float* out = (float*)d_out;                 // (1024, 32)
    int nveh = in_sizes[0] / 3;
    int nfus = in_sizes[1] / 3;
    shape_context_kernel<<<nveh, BLOCK, 0, stream>>>(veh, fus, out, nfus);
}